// Round 7
// baseline (237.560 us; speedup 1.0000x reference)
//
#include <hip/hip_runtime.h>
#include <math.h>

#define BB 2
#define TT 2048
#define DD 1024
#define NH 16
#define NKV 4
#define HD 64
#define EPSF 1.1920929e-07f
// T=2048 > TSL=1024 -> nb = 10000 * 2^(64/62); log2(nb) = log2(1e4) + 64/62
#define LOG2_NB 14.319970444065578
// 0.125 (1/sqrt(64)) * log2(e): folded into q so softmax runs in exp2 domain
#define SCALE_LOG2E 0.18033688011112042f
// fixed softmax max (exp2 units): |q.k| <= 8*8*1.5*0.125*log2e = 17.31 < 17.5
#define FIXMAX 17.5f

typedef __attribute__((ext_vector_type(8))) short bf16x8;
typedef __attribute__((ext_vector_type(4))) float f32x4;

__device__ inline short f2bf(float f) {
    unsigned u = __builtin_bit_cast(unsigned, f);
    unsigned r = (u + 0x7fffu + ((u >> 16) & 1u)) >> 16;
    return (short)r;
}

// ---------------- fused fp32 -> bf16 conversion for all 5 tensors ----------------
__global__ __launch_bounds__(256) void conv_all(
    const float* __restrict__ x, const float* __restrict__ qw,
    const float* __restrict__ kw, const float* __restrict__ vw,
    const float* __restrict__ ow,
    short* __restrict__ x16, short* __restrict__ wb16, short* __restrict__ ow16)
{
    int i = blockIdx.x * 256 + threadIdx.x;   // float4 index, total 1703936
    const float* src; short* dst; int j;
    if (i < 1048576)      { src = x;  dst = x16;            j = i; }
    else if (i < 1310720) { src = qw; dst = wb16;           j = i - 1048576; }
    else if (i < 1376256) { src = kw; dst = wb16 + 1048576; j = i - 1310720; }
    else if (i < 1441792) { src = vw; dst = wb16 + 1310720; j = i - 1376256; }
    else                  { src = ow; dst = ow16;           j = i - 1441792; }
    float4 v = ((const float4*)src)[j];
    short4 o;
    o.x = f2bf(v.x); o.y = f2bf(v.y); o.z = f2bf(v.z); o.w = f2bf(v.w);
    ((short4*)dst)[j] = o;
}

// ---------------- bf16 MFMA GEMM, prefetch double-buffered: C = A * B^T ----------------
// 128x128 tile, BK=32, 256 threads = 4 waves (2x2 of 64x64). Stage tile k+1 while
// computing tile k; ONE barrier per K-step (its implicit vmcnt(0) drains the DMA
// that has had the whole compute phase in flight).
__global__ __launch_bounds__(256, 4) void gemm_mfma(
    const short* __restrict__ A, const short* __restrict__ Bmat,
    const float* __restrict__ ve, float* __restrict__ C, int ldc)
{
    __shared__ short As[2][128*32];
    __shared__ short Bs[2][128*32];
    int tid = threadIdx.x;
    int w = tid >> 6, lane = tid & 63;
    int quad = lane >> 4, lc = lane & 15;
    int wy = w >> 1, wx = w & 1;
    int m0 = blockIdx.y * 128, n0 = blockIdx.x * 128;

    f32x4 acc[4][4];
    #pragma unroll
    for (int i = 0; i < 4; i++)
        #pragma unroll
        for (int j = 0; j < 4; j++) acc[i][j] = (f32x4){0.f,0.f,0.f,0.f};

    // stage 8KB of A and B for K-slice k0 into buffer buf (XOR-swizzled 16B chunks)
    #define GSTAGE(buf, k0)                                                             \
    {                                                                                   \
        _Pragma("unroll")                                                               \
        for (int i = 0; i < 2; i++) {                                                   \
            int off = w*2048 + i*1024;            /* byte offset, wave-uniform */       \
            int g = (off >> 4) + lane;            /* 16B chunk idx */                   \
            int row = g >> 2, c = g & 3;                                                \
            int cg = c ^ (row & 3);                                                     \
            const short* ga = A + (size_t)(m0 + row)*1024 + (k0) + cg*8;                \
            __builtin_amdgcn_global_load_lds(                                           \
                (const __attribute__((address_space(1))) void*)ga,                      \
                (__attribute__((address_space(3))) void*)((char*)&As[buf][0] + off), 16, 0, 0); \
            const short* gb = Bmat + (size_t)(n0 + row)*1024 + (k0) + cg*8;             \
            __builtin_amdgcn_global_load_lds(                                           \
                (const __attribute__((address_space(1))) void*)gb,                      \
                (__attribute__((address_space(3))) void*)((char*)&Bs[buf][0] + off), 16, 0, 0); \
        }                                                                               \
    }

    GSTAGE(0, 0);
    __syncthreads();

    for (int k0 = 0; k0 < 1024; k0 += 32) {
        int cur = (k0 >> 5) & 1;
        if (k0 < 992) GSTAGE(cur ^ 1, k0 + 32);

        bf16x8 af[4], bfr[4];
        #pragma unroll
        for (int tm = 0; tm < 4; tm++) {
            int row = wy*64 + tm*16 + lc;
            af[tm] = *(const bf16x8*)(&As[cur][0] + row*32 + ((quad*8) ^ ((row&3)*8)));
        }
        #pragma unroll
        for (int tn = 0; tn < 4; tn++) {
            int row = wx*64 + tn*16 + lc;
            bfr[tn] = *(const bf16x8*)(&Bs[cur][0] + row*32 + ((quad*8) ^ ((row&3)*8)));
        }
        #pragma unroll
        for (int tm = 0; tm < 4; tm++)
            #pragma unroll
            for (int tn = 0; tn < 4; tn++)
                acc[tm][tn] = __builtin_amdgcn_mfma_f32_16x16x32_bf16(af[tm], bfr[tn], acc[tm][tn], 0, 0, 0);
        __syncthreads();
    }

    #pragma unroll
    for (int tm = 0; tm < 4; tm++)
        #pragma unroll
        for (int r = 0; r < 4; r++) {
            int m = m0 + wy*64 + tm*16 + quad*4 + r;
            #pragma unroll
            for (int tn = 0; tn < 4; tn++) {
                int n = n0 + wx*64 + tn*16 + lc;
                float v = acc[tm][tn][r];
                if (ve && n >= 1280) v += ve[(size_t)m*256 + (n - 1280)];
                C[(size_t)m*ldc + n] = v;
            }
        }
}

// ---------------- epilogue: RMSNorm + RoPE + gain*scale (q,k) -> bf16; v mix -> bf16 ----------------
__global__ __launch_bounds__(256) void qkv_epilogue(
    const float* __restrict__ qkv, const float* __restrict__ v0,
    const float* __restrict__ q_gain, const float* __restrict__ vr_lambda,
    short* __restrict__ qbh, short* __restrict__ kbh, short* __restrict__ vb,
    float* __restrict__ rawv)
{
    int wave = blockIdx.x * 4 + (threadIdx.x >> 6);
    int lane = threadIdx.x & 63;
    int row = wave / 24;     // 0..4095  (b*T + t)
    int hh  = wave % 24;
    int b = row >> 11;
    int t = row & (TT - 1);

    if (hh < 20) {
        int col = (hh < 16) ? (hh*64 + lane) : (1024 + (hh-16)*64 + lane);
        float val = qkv[(size_t)row*1536 + col];
        float ss = val * val;
        #pragma unroll
        for (int off = 32; off; off >>= 1) ss += __shfl_xor(ss, off);
        val *= rsqrtf(ss * (1.0f/64.0f) + EPSF);
        float partner = __shfl(val, lane ^ 32);
        int idx = lane & 31;
        float inv = (float)exp2((double)idx * (-LOG2_NB / 32.0));
        float fr = (float)t * inv;
        float sn, cs;
        sincosf(fr, &sn, &cs);
        float outv = (lane < 32) ? (val*cs + partner*sn) : (val*cs - partner*sn);
        if (hh < 16) {
            outv *= q_gain[hh] * SCALE_LOG2E;    // fold softmax scale+log2e into q
            qbh[(((size_t)(b*16 + hh))*2048 + t)*64 + lane] = f2bf(outv);
        } else {
            kbh[(((size_t)(b*4 + (hh-16)))*2048 + t)*64 + lane] = f2bf(outv);
        }
    } else {
        int vh = hh - 20;
        size_t off = ((size_t)row*4 + vh)*64 + lane;
        float vraw = qkv[(size_t)row*1536 + 1280 + vh*64 + lane];
        rawv[off] = vraw;
        float vmix = vr_lambda[0]*v0[off] + vr_lambda[1]*vraw;
        vb[off] = f2bf(vmix);                    // coalesced [b][t][kvh][d]
    }
}

// ---------------- V transpose: vb [b][t][kvh][d] -> vtb [b*4+kvh][d][t] ----------------
__global__ __launch_bounds__(256) void transpose_v(
    const short* __restrict__ vb, short* __restrict__ vtb)
{
    __shared__ short tile[64][72];
    int bk = blockIdx.x;           // b*4+kvh
    int tt = blockIdx.y;           // t tile (64)
    int b = bk >> 2, kvh = bk & 3;
    int tid = threadIdx.x;
    int t4 = tid >> 4;             // 0..15
    int d4 = (tid & 15) * 4;       // 0..60
    #pragma unroll
    for (int i = 0; i < 4; i++) {
        int t = t4 + i*16;
        const short* src = vb + (((size_t)(b*2048 + tt*64 + t)*4 + kvh)*64 + d4);
        *(short4*)&tile[t][d4] = *(const short4*)src;
    }
    __syncthreads();
    #pragma unroll
    for (int i = 0; i < 4; i++) {
        int d = t4 + i*16;
        int t0 = d4;
        short4 o;
        o.x = tile[t0+0][d]; o.y = tile[t0+1][d];
        o.z = tile[t0+2][d]; o.w = tile[t0+3][d];
        *(short4*)&vtb[((size_t)(bk*64 + d))*2048 + tt*64 + t0] = o;
    }
}

// ---------------- gate: sigmoid(x @ gate_w.T + gate_b) ----------------
__global__ __launch_bounds__(256) void gate_kernel(
    const float* __restrict__ x, const float* __restrict__ gw,
    const float* __restrict__ gb, float* __restrict__ gate)
{
    __shared__ float xs[1024];
    int row = blockIdx.x;
    int tid = threadIdx.x;
    *(float4*)&xs[tid*4] = *(const float4*)&x[(size_t)row*1024 + tid*4];
    __syncthreads();
    int wave = tid >> 6, lane = tid & 63;
    for (int h = wave; h < 16; h += 4) {
        const float* w = gw + (size_t)h * 1024;
        float s = 0.f;
        #pragma unroll
        for (int i = 0; i < 16; i++) s += xs[lane + 64*i] * w[lane + 64*i];
        #pragma unroll
        for (int off = 32; off; off >>= 1) s += __shfl_xor(s, off);
        if (lane == 0) gate[(size_t)row*16 + h] = 1.0f / (1.0f + __expf(-(s + gb[h])));
    }
}

// ---------------- MFMA flash attention: fixed-max softmax, 1 q-tile/block, dbuf, swizzled LDS ----------------
__device__ inline void flash_step(
    const short* __restrict__ KsBuf, const short* __restrict__ VtBuf, short* __restrict__ ps,
    bf16x8 qf0, bf16x8 qf1,
    f32x4 (&o)[4], float (&l_lane)[4],
    int quad, int lc, int rowbase, bool diag)
{
    // S = Q K^T (exp2-domain scores: scale folded into Q)
    f32x4 s4[4];
    #pragma unroll
    for (int kn = 0; kn < 4; kn++) {
        int row = kn*16 + lc;
        const short* kr = KsBuf + row*64;
        int sw = (row & 7) * 8;
        bf16x8 kf0 = *(const bf16x8*)(kr + ((quad*8) ^ sw));
        bf16x8 kf1 = *(const bf16x8*)(kr + ((quad*8 + 32) ^ sw));
        f32x4 acc = (f32x4){0.f,0.f,0.f,0.f};
        acc = __builtin_amdgcn_mfma_f32_16x16x32_bf16(qf0, kf0, acc, 0, 0, 0);
        acc = __builtin_amdgcn_mfma_f32_16x16x32_bf16(qf1, kf1, acc, 0, 0, 0);
        s4[kn] = acc;
    }
    // p = exp2(s - FIXMAX); mask; accumulate l per-lane; write swizzled bf16 P
    #pragma unroll
    for (int kn = 0; kn < 4; kn++)
        #pragma unroll
        for (int r = 0; r < 4; r++) {
            float p = exp2f(s4[kn][r] - FIXMAX);
            if (diag && (kn*16 + lc > rowbase + quad*4 + r)) p = 0.f;
            l_lane[r] += p;
            int prow = quad*4 + r;
            int chunk = (kn*2 + (lc >> 3)) ^ (prow & 7);
            ps[prow*64 + chunk*8 + (lc & 7)] = f2bf(p);
        }
    __asm__ volatile("s_waitcnt lgkmcnt(0)" ::: "memory");
    int psw = lc & 7;
    bf16x8 pf0 = *(const bf16x8*)(ps + lc*64 + ((quad ^ psw) * 8));
    bf16x8 pf1 = *(const bf16x8*)(ps + lc*64 + (((quad + 4) ^ psw) * 8));

    #pragma unroll
    for (int dn = 0; dn < 4; dn++) {
        int row = dn*16 + lc;
        const short* vr = VtBuf + row*64;
        int sw = (row & 7) * 8;
        bf16x8 vf0 = *(const bf16x8*)(vr + ((quad*8) ^ sw));
        bf16x8 vf1 = *(const bf16x8*)(vr + ((quad*8 + 32) ^ sw));
        o[dn] = __builtin_amdgcn_mfma_f32_16x16x32_bf16(pf0, vf0, o[dn], 0, 0, 0);
        o[dn] = __builtin_amdgcn_mfma_f32_16x16x32_bf16(pf1, vf1, o[dn], 0, 0, 0);
    }
}

__global__ __launch_bounds__(256, 4) void flash_mfma(
    const short* __restrict__ qbh, const short* __restrict__ kbh,
    const short* __restrict__ vtb, const float* __restrict__ gate,
    short* __restrict__ y16)
{
    __shared__ short Ks[2][64*64];
    __shared__ short Vt[2][64*64];
    __shared__ short Ps[4][16*64];

    int bh = blockIdx.x;             // b*16 + h
    int b = bh >> 4, h = bh & 15, kvh = h >> 2;
    int qt = 31 - blockIdx.y;        // long blocks launch first (backfill-friendly)
    int tid = threadIdx.x;
    int w = tid >> 6, lane = tid & 63;
    int quad = lane >> 4, lc = lane & 15;

    const short* qbase = qbh + (((size_t)bh)*2048 + qt*64 + w*16 + lc)*64;
    bf16x8 qf0 = *(const bf16x8*)(qbase + quad*8);
    bf16x8 qf1 = *(const bf16x8*)(qbase + 32 + quad*8);

    f32x4 o[4];
    float l_lane[4];
    #pragma unroll
    for (int i = 0; i < 4; i++) { o[i] = (f32x4){0.f,0.f,0.f,0.f}; l_lane[i] = 0.f; }

    const size_t kbase = ((size_t)(b*4 + kvh))*2048*64;   // K [t][d]
    const size_t vbase = ((size_t)(b*4 + kvh))*64*2048;   // V^T [d][t]

    #define STAGE(buf, kt)                                                              \
    {                                                                                   \
        _Pragma("unroll")                                                               \
        for (int i = 0; i < 2; i++) {                                                   \
            int off = w*2048 + i*1024;                                                  \
            int g = (off >> 4) + lane;                                                  \
            int row = g >> 3, c = g & 7;                                                \
            int cg = c ^ (row & 7);                                                     \
            const short* gk = kbh + kbase + (size_t)((kt)*64 + row)*64 + cg*8;          \
            __builtin_amdgcn_global_load_lds(                                           \
                (const __attribute__((address_space(1))) void*)gk,                      \
                (__attribute__((address_space(3))) void*)((char*)Ks[buf] + off), 16, 0, 0); \
            const short* gv = vtb + vbase + (size_t)row*2048 + (kt)*64 + cg*8;          \
            __builtin_amdgcn_global_load_lds(                                           \
                (const __attribute__((address_space(1))) void*)gv,                      \
                (__attribute__((address_space(3))) void*)((char*)Vt[buf] + off), 16, 0, 0); \
        }                                                                               \
    }

    STAGE(0, 0);
    __syncthreads();

    for (int kt = 0; kt <= qt; kt++) {
        int cur = kt & 1;
        if (kt < qt) STAGE(cur ^ 1, kt + 1);
        flash_step(Ks[cur], Vt[cur], Ps[w], qf0, qf1, o, l_lane, quad, lc, w*16, kt == qt);
        __syncthreads();
    }

    // reduce l across the 16 cols (lc lanes within each quad)
    float l_r[4];
    #pragma unroll
    for (int r = 0; r < 4; r++) {
        float rs = l_lane[r];
        #pragma unroll
        for (int off = 1; off < 16; off <<= 1) rs += __shfl_xor(rs, off);
        l_r[r] = rs;
    }

    #pragma unroll
    for (int r = 0; r < 4; r++) {
        int row = b*2048 + qt*64 + w*16 + quad*4 + r;
        float g = gate[(size_t)row*16 + h] / l_r[r];
        #pragma unroll
        for (int dn = 0; dn < 4; dn++)
            y16[(size_t)row*1024 + h*64 + dn*16 + lc] = f2bf(o[dn][r] * g);
    }
}

extern "C" void kernel_launch(void* const* d_in, const int* in_sizes, int n_in,
                              void* d_out, int out_size, void* d_ws, size_t ws_size,
                              hipStream_t stream) {
    (void)in_sizes; (void)n_in; (void)out_size; (void)ws_size;
    const float* x  = (const float*)d_in[0];
    const float* qw = (const float*)d_in[1];
    const float* kw = (const float*)d_in[2];
    const float* vw = (const float*)d_in[3];
    const float* ow = (const float*)d_in[4];
    const float* ve = (const float*)d_in[5];
    const float* v0 = (const float*)d_in[6];
    const float* qg = (const float*)d_in[7];
    const float* vl = (const float*)d_in[8];
    const float* gw = (const float*)d_in[9];
    const float* gb = (const float*)d_in[10];

    float* out  = (float*)d_out;
    float* rawv = out + (size_t)BB*TT*DD;

    // workspace layout (float units)
    float* ws   = (float*)d_ws;
    float* qkv  = ws;                               // 4096*1536 f32; y16 reuses later
    float* p    = ws + 6291456;
    short* x16  = (short*)p;        p += 2097152;   // 4096*1024 bf16
    short* wb16 = (short*)p;        p += 786432;    // 1536*1024 bf16 (qw|kw|vw)
    short* ow16 = (short*)p;        p += 524288;    // 1024*1024 bf16
    short* qbh  = (short*)p;        p += 2097152;   // [b*16+h][t][d] bf16
    short* kbh  = (short*)p;        p += 524288;    // [b*4+kvh][t][d] bf16
    short* vtb  = (short*)p;        p += 524288;    // [b*4+kvh][d][t] bf16
    short* vb   = (short*)p;        p += 524288;    // [b][t][kvh][d] bf16 (pre-transpose)
    float* gt   = p;                                // 4096*16 f32
    short* y16  = (short*)qkv;

    conv_all<<<6656, 256, 0, stream>>>(x, qw, kw, vw, ow, x16, wb16, ow16);
    // QKV projection: M=4096, N=1536
    gemm_mfma<<<dim3(12, 32), 256, 0, stream>>>(x16, wb16, ve, qkv, 1536);
    qkv_epilogue<<<24576, 256, 0, stream>>>(qkv, v0, qg, vl, qbh, kbh, vb, rawv);
    transpose_v<<<dim3(8, 32), 256, 0, stream>>>(vb, vtb);
    gate_kernel<<<4096, 256, 0, stream>>>(x, gw, gb, gt);
    flash_mfma<<<dim3(32, 32), 256, 0, stream>>>(qbh, kbh, vtb, gt, y16);
    // out projection: M=4096, N=1024
    gemm_mfma<<<dim3(8, 32), 256, 0, stream>>>(y16, ow16, nullptr, out, 1024);
}

// Round 8
// 218.200 us; speedup vs baseline: 1.0887x; 1.0887x over previous
//
#include <hip/hip_runtime.h>
#include <math.h>

#define BB 2
#define TT 2048
#define DD 1024
#define NH 16
#define NKV 4
#define HD 64
#define EPSF 1.1920929e-07f
// T=2048 > TSL=1024 -> nb = 10000 * 2^(64/62); log2(nb) = log2(1e4) + 64/62
#define LOG2_NB 14.319970444065578
// 0.125 (1/sqrt(64)) * log2(e): folded into q so softmax runs in exp2 domain
#define SCALE_LOG2E 0.18033688011112042f
// fixed softmax max (exp2 units): |q.k| <= 8*8*1.5*0.125*log2e = 17.31 < 17.5
#define FIXMAX 17.5f

typedef __attribute__((ext_vector_type(8))) short bf16x8;
typedef __attribute__((ext_vector_type(4))) float f32x4;

__device__ inline short f2bf(float f) {
    unsigned u = __builtin_bit_cast(unsigned, f);
    unsigned r = (u + 0x7fffu + ((u >> 16) & 1u)) >> 16;
    return (short)r;
}
__device__ inline unsigned pack_bf2(float a, float b) {
    return (unsigned)(unsigned short)f2bf(a) | ((unsigned)(unsigned short)f2bf(b) << 16);
}

// ---------------- fused fp32 -> bf16 conversion for all 5 tensors ----------------
__global__ __launch_bounds__(256) void conv_all(
    const float* __restrict__ x, const float* __restrict__ qw,
    const float* __restrict__ kw, const float* __restrict__ vw,
    const float* __restrict__ ow,
    short* __restrict__ x16, short* __restrict__ wb16, short* __restrict__ ow16)
{
    int i = blockIdx.x * 256 + threadIdx.x;   // float4 index, total 1703936
    const float* src; short* dst; int j;
    if (i < 1048576)      { src = x;  dst = x16;            j = i; }
    else if (i < 1310720) { src = qw; dst = wb16;           j = i - 1048576; }
    else if (i < 1376256) { src = kw; dst = wb16 + 1048576; j = i - 1310720; }
    else if (i < 1441792) { src = vw; dst = wb16 + 1310720; j = i - 1376256; }
    else                  { src = ow; dst = ow16;           j = i - 1441792; }
    float4 v = ((const float4*)src)[j];
    short4 o;
    o.x = f2bf(v.x); o.y = f2bf(v.y); o.z = f2bf(v.z); o.w = f2bf(v.w);
    ((short4*)dst)[j] = o;
}

// ---------------- bf16 MFMA GEMM: C = A * B^T over K range [z*klen, (z+1)*klen) ----------------
// 128x128 tile, BK=32, 256 threads = 4 waves. Order per K-step: LDS frag reads ->
// prefetch DMA for next step -> MFMAs -> barrier (vmcnt(0) drain sits AFTER compute).
__global__ __launch_bounds__(256, 4) void gemm_mfma(
    const short* __restrict__ A, const short* __restrict__ Bmat,
    float* __restrict__ C, int ldc, int klen)
{
    __shared__ short As[2][128*32];
    __shared__ short Bs[2][128*32];
    int tid = threadIdx.x;
    int w = tid >> 6, lane = tid & 63;
    int quad = lane >> 4, lc = lane & 15;
    int wy = w >> 1, wx = w & 1;
    int m0 = blockIdx.y * 128, n0 = blockIdx.x * 128;
    int kbeg = blockIdx.z * klen, kend = kbeg + klen;
    float* Cz = C + (size_t)blockIdx.z * 4096 * ldc;

    f32x4 acc[4][4];
    #pragma unroll
    for (int i = 0; i < 4; i++)
        #pragma unroll
        for (int j = 0; j < 4; j++) acc[i][j] = (f32x4){0.f,0.f,0.f,0.f};

    #define GSTAGE(buf, k0)                                                             \
    {                                                                                   \
        _Pragma("unroll")                                                               \
        for (int i = 0; i < 2; i++) {                                                   \
            int off = w*2048 + i*1024;            /* byte offset, wave-uniform */       \
            int g = (off >> 4) + lane;            /* 16B chunk idx */                   \
            int row = g >> 2, c = g & 3;                                                \
            int cg = c ^ (row & 3);               /* XOR swizzle */                     \
            const short* ga = A + (size_t)(m0 + row)*1024 + (k0) + cg*8;                \
            __builtin_amdgcn_global_load_lds(                                           \
                (const __attribute__((address_space(1))) void*)ga,                      \
                (__attribute__((address_space(3))) void*)((char*)&As[buf][0] + off), 16, 0, 0); \
            const short* gb = Bmat + (size_t)(n0 + row)*1024 + (k0) + cg*8;             \
            __builtin_amdgcn_global_load_lds(                                           \
                (const __attribute__((address_space(1))) void*)gb,                      \
                (__attribute__((address_space(3))) void*)((char*)&Bs[buf][0] + off), 16, 0, 0); \
        }                                                                               \
    }

    GSTAGE(0, kbeg);
    __syncthreads();

    for (int k0 = kbeg; k0 < kend; k0 += 32) {
        int cur = ((k0 - kbeg) >> 5) & 1;

        // 1. LDS -> register fragment reads (before any new DMA is issued)
        bf16x8 af[4], bfr[4];
        #pragma unroll
        for (int tm = 0; tm < 4; tm++) {
            int row = wy*64 + tm*16 + lc;
            af[tm] = *(const bf16x8*)(&As[cur][0] + row*32 + ((quad*8) ^ ((row&3)*8)));
        }
        #pragma unroll
        for (int tn = 0; tn < 4; tn++) {
            int row = wx*64 + tn*16 + lc;
            bfr[tn] = *(const bf16x8*)(&Bs[cur][0] + row*32 + ((quad*8) ^ ((row&3)*8)));
        }
        // 2. prefetch next K-slice
        if (k0 + 32 < kend) GSTAGE(cur ^ 1, k0 + 32);
        // 3. compute
        #pragma unroll
        for (int tm = 0; tm < 4; tm++)
            #pragma unroll
            for (int tn = 0; tn < 4; tn++)
                acc[tm][tn] = __builtin_amdgcn_mfma_f32_16x16x32_bf16(af[tm], bfr[tn], acc[tm][tn], 0, 0, 0);
        // 4. barrier: drains the prefetch DMA after compute had its window
        __syncthreads();
    }

    #pragma unroll
    for (int tm = 0; tm < 4; tm++)
        #pragma unroll
        for (int r = 0; r < 4; r++) {
            int m = m0 + wy*64 + tm*16 + quad*4 + r;
            #pragma unroll
            for (int tn = 0; tn < 4; tn++) {
                int n = n0 + wx*64 + tn*16 + lc;
                Cz[(size_t)m*ldc + n] = acc[tm][tn][r];
            }
        }
}

// ---------------- epilogue: sum split-K partials; RMSNorm + RoPE + gain*scale (q,k) -> bf16;
// ---------------- v = p0+p1+ve, mix -> bf16; raw_v fp32 ----------------
__global__ __launch_bounds__(256) void qkv_epilogue(
    const float* __restrict__ qp0, const float* __restrict__ qp1,
    const float* __restrict__ ve, const float* __restrict__ v0,
    const float* __restrict__ q_gain, const float* __restrict__ vr_lambda,
    short* __restrict__ qbh, short* __restrict__ kbh, short* __restrict__ vb,
    float* __restrict__ rawv)
{
    int wave = blockIdx.x * 4 + (threadIdx.x >> 6);
    int lane = threadIdx.x & 63;
    int row = wave / 24;     // 0..4095  (b*T + t)
    int hh  = wave % 24;
    int b = row >> 11;
    int t = row & (TT - 1);

    if (hh < 20) {
        int col = (hh < 16) ? (hh*64 + lane) : (1024 + (hh-16)*64 + lane);
        size_t idx = (size_t)row*1536 + col;
        float val = qp0[idx] + qp1[idx];
        float ss = val * val;
        #pragma unroll
        for (int off = 32; off; off >>= 1) ss += __shfl_xor(ss, off);
        val *= rsqrtf(ss * (1.0f/64.0f) + EPSF);
        float partner = __shfl(val, lane ^ 32);
        int idxr = lane & 31;
        float inv = (float)exp2((double)idxr * (-LOG2_NB / 32.0));
        float fr = (float)t * inv;
        float sn, cs;
        sincosf(fr, &sn, &cs);
        float outv = (lane < 32) ? (val*cs + partner*sn) : (val*cs - partner*sn);
        if (hh < 16) {
            outv *= q_gain[hh] * SCALE_LOG2E;    // fold softmax scale+log2e into q
            qbh[(((size_t)(b*16 + hh))*2048 + t)*64 + lane] = f2bf(outv);
        } else {
            kbh[(((size_t)(b*4 + (hh-16)))*2048 + t)*64 + lane] = f2bf(outv);
        }
    } else {
        int vh = hh - 20;
        size_t off = ((size_t)row*4 + vh)*64 + lane;
        size_t idx = (size_t)row*1536 + 1280 + vh*64 + lane;
        float vraw = qp0[idx] + qp1[idx] + ve[off];
        rawv[off] = vraw;
        float vmix = vr_lambda[0]*v0[off] + vr_lambda[1]*vraw;
        vb[off] = f2bf(vmix);                    // coalesced [b][t][kvh][d]
    }
}

// ---------------- V transpose: vb [b][t][kvh][d] -> vtb [b*4+kvh][d][t] ----------------
__global__ __launch_bounds__(256) void transpose_v(
    const short* __restrict__ vb, short* __restrict__ vtb)
{
    __shared__ short tile[64][72];
    int bk = blockIdx.x;           // b*4+kvh
    int tt = blockIdx.y;           // t tile (64)
    int b = bk >> 2, kvh = bk & 3;
    int tid = threadIdx.x;
    int t4 = tid >> 4;             // 0..15
    int d4 = (tid & 15) * 4;       // 0..60
    #pragma unroll
    for (int i = 0; i < 4; i++) {
        int t = t4 + i*16;
        const short* src = vb + (((size_t)(b*2048 + tt*64 + t)*4 + kvh)*64 + d4);
        *(short4*)&tile[t][d4] = *(const short4*)src;
    }
    __syncthreads();
    #pragma unroll
    for (int i = 0; i < 4; i++) {
        int d = t4 + i*16;
        int t0 = d4;
        short4 o;
        o.x = tile[t0+0][d]; o.y = tile[t0+1][d];
        o.z = tile[t0+2][d]; o.w = tile[t0+3][d];
        *(short4*)&vtb[((size_t)(bk*64 + d))*2048 + tt*64 + t0] = o;
    }
}

// ---------------- gate: sigmoid(x @ gate_w.T + gate_b) ----------------
__global__ __launch_bounds__(256) void gate_kernel(
    const float* __restrict__ x, const float* __restrict__ gw,
    const float* __restrict__ gb, float* __restrict__ gate)
{
    __shared__ float xs[1024];
    int row = blockIdx.x;
    int tid = threadIdx.x;
    *(float4*)&xs[tid*4] = *(const float4*)&x[(size_t)row*1024 + tid*4];
    __syncthreads();
    int wave = tid >> 6, lane = tid & 63;
    for (int h = wave; h < 16; h += 4) {
        const float* w = gw + (size_t)h * 1024;
        float s = 0.f;
        #pragma unroll
        for (int i = 0; i < 16; i++) s += xs[lane + 64*i] * w[lane + 64*i];
        #pragma unroll
        for (int off = 32; off; off >>= 1) s += __shfl_xor(s, off);
        if (lane == 0) gate[(size_t)row*16 + h] = 1.0f / (1.0f + __expf(-(s + gb[h])));
    }
}

// ---------------- MFMA flash attention v3 ----------------
// Computes S^T = K Q^T so the C-layout gives each lane 4 CONSECUTIVE keys at fixed q:
// P pack = 4x ds_write_b64 (+2x ds_read_b128), l = single per-lane scalar.
// Per step: frag preload -> prefetch DMA -> QK MFMAs -> softmax/pack -> PV MFMAs -> barrier.
__global__ __launch_bounds__(256, 4) void flash_mfma(
    const short* __restrict__ qbh, const short* __restrict__ kbh,
    const short* __restrict__ vtb, const float* __restrict__ gate,
    short* __restrict__ y16)
{
    __shared__ short Ks[2][64*64];
    __shared__ short Vt[2][64*64];
    __shared__ short Ps[4][16*64];   // per wave: row q=lc (16), 64 keys; 8B-chunk XOR swizzle

    int bh = blockIdx.x;             // b*16 + h
    int b = bh >> 4, h = bh & 15, kvh = h >> 2;
    int qt = 31 - blockIdx.y;        // long blocks launch first
    int tid = threadIdx.x;
    int w = tid >> 6, lane = tid & 63;
    int quad = lane >> 4, lc = lane & 15;

    const short* qbase = qbh + (((size_t)bh)*2048 + qt*64 + w*16 + lc)*64;
    bf16x8 qf0 = *(const bf16x8*)(qbase + quad*8);
    bf16x8 qf1 = *(const bf16x8*)(qbase + 32 + quad*8);

    f32x4 o[4];
    #pragma unroll
    for (int i = 0; i < 4; i++) o[i] = (f32x4){0.f,0.f,0.f,0.f};
    float l_lane = 0.f;

    const size_t kbase = ((size_t)(b*4 + kvh))*2048*64;   // K [t][d]
    const size_t vbase = ((size_t)(b*4 + kvh))*64*2048;   // V^T [d][t]

    #define STAGE(buf, kt)                                                              \
    {                                                                                   \
        _Pragma("unroll")                                                               \
        for (int i = 0; i < 2; i++) {                                                   \
            int off = w*2048 + i*1024;                                                  \
            int g = (off >> 4) + lane;                                                  \
            int row = g >> 3, c = g & 7;                                                \
            int cg = c ^ (row & 7);                                                     \
            const short* gk = kbh + kbase + (size_t)((kt)*64 + row)*64 + cg*8;          \
            __builtin_amdgcn_global_load_lds(                                           \
                (const __attribute__((address_space(1))) void*)gk,                      \
                (__attribute__((address_space(3))) void*)((char*)Ks[buf] + off), 16, 0, 0); \
            const short* gv = vtb + vbase + (size_t)row*2048 + (kt)*64 + cg*8;          \
            __builtin_amdgcn_global_load_lds(                                           \
                (const __attribute__((address_space(1))) void*)gv,                      \
                (__attribute__((address_space(3))) void*)((char*)Vt[buf] + off), 16, 0, 0); \
        }                                                                               \
    }

    STAGE(0, 0);
    __syncthreads();

    short* ps = Ps[w];

    for (int kt = 0; kt <= qt; kt++) {
        int cur = kt & 1;
        bool diag = (kt == qt);

        // 1. preload ALL K/V fragments for this tile (no LDS reads after DMA issue)
        bf16x8 kf0[4], kf1[4], vf0[4], vf1[4];
        #pragma unroll
        for (int kn = 0; kn < 4; kn++) {
            int row = kn*16 + lc;
            int sw = (row & 7) * 8;
            const short* kr = Ks[cur] + row*64;
            kf0[kn] = *(const bf16x8*)(kr + ((quad*8) ^ sw));
            kf1[kn] = *(const bf16x8*)(kr + ((quad*8 + 32) ^ sw));
            const short* vr = Vt[cur] + row*64;
            vf0[kn] = *(const bf16x8*)(vr + ((quad*8) ^ sw));
            vf1[kn] = *(const bf16x8*)(vr + ((quad*8 + 32) ^ sw));
        }
        // 2. prefetch next K/V tile
        if (kt < qt) STAGE(cur ^ 1, kt + 1);

        // 3. S^T = K Q^T : lane holds cols q=lc, rows key = kn*16 + quad*4 + r
        f32x4 s4[4];
        #pragma unroll
        for (int kn = 0; kn < 4; kn++) {
            f32x4 acc = (f32x4){0.f,0.f,0.f,0.f};
            acc = __builtin_amdgcn_mfma_f32_16x16x32_bf16(kf0[kn], qf0, acc, 0, 0, 0);
            acc = __builtin_amdgcn_mfma_f32_16x16x32_bf16(kf1[kn], qf1, acc, 0, 0, 0);
            s4[kn] = acc;
        }

        // 4. p = exp2(s - FIXMAX), causal mask, l accumulate, packed b64 P store
        #pragma unroll
        for (int kn = 0; kn < 4; kn++) {
            float p0 = exp2f(s4[kn][0] - FIXMAX);
            float p1 = exp2f(s4[kn][1] - FIXMAX);
            float p2 = exp2f(s4[kn][2] - FIXMAX);
            float p3 = exp2f(s4[kn][3] - FIXMAX);
            if (diag) {
                int keyb = kn*16 + quad*4, qv = w*16 + lc;
                if (keyb + 0 > qv) p0 = 0.f;
                if (keyb + 1 > qv) p1 = 0.f;
                if (keyb + 2 > qv) p2 = 0.f;
                if (keyb + 3 > qv) p3 = 0.f;
            }
            l_lane += (p0 + p1) + (p2 + p3);
            int c = kn*4 + quad;
            int cs = c ^ ((lc & 7) << 1);
            int2 pk;
            pk.x = (int)pack_bf2(p0, p1);
            pk.y = (int)pack_bf2(p2, p3);
            *(int2*)(ps + lc*64 + cs*4) = pk;
        }
        __asm__ volatile("s_waitcnt lgkmcnt(0)" ::: "memory");
        // P A-frags: row q=lc, keys kh*32 + quad*8 + (0..7)
        int u0 = (0*4 + quad) ^ (lc & 7);
        int u1 = (1*4 + quad) ^ (lc & 7);
        bf16x8 pf0 = *(const bf16x8*)(ps + lc*64 + u0*8);
        bf16x8 pf1 = *(const bf16x8*)(ps + lc*64 + u1*8);

        // 5. O += P V : o rows q = quad*4+r, cols d = dn*16+lc
        #pragma unroll
        for (int dn = 0; dn < 4; dn++) {
            o[dn] = __builtin_amdgcn_mfma_f32_16x16x32_bf16(pf0, vf0[dn], o[dn], 0, 0, 0);
            o[dn] = __builtin_amdgcn_mfma_f32_16x16x32_bf16(pf1, vf1[dn], o[dn], 0, 0, 0);
        }
        __syncthreads();
    }

    // l: sum across quads (lanes lc, lc+16, lc+32, lc+48 all hold q=lc partials)
    l_lane += __shfl_xor(l_lane, 16);
    l_lane += __shfl_xor(l_lane, 32);
    // redistribute: lane needs l for q = quad*4 + r
    float l_r[4];
    #pragma unroll
    for (int r = 0; r < 4; r++) l_r[r] = __shfl(l_lane, quad*4 + r);

    #pragma unroll
    for (int r = 0; r < 4; r++) {
        int row = b*2048 + qt*64 + w*16 + quad*4 + r;
        float g = gate[(size_t)row*16 + h] / l_r[r];
        #pragma unroll
        for (int dn = 0; dn < 4; dn++)
            y16[(size_t)row*1024 + h*64 + dn*16 + lc] = f2bf(o[dn][r] * g);
    }
}

extern "C" void kernel_launch(void* const* d_in, const int* in_sizes, int n_in,
                              void* d_out, int out_size, void* d_ws, size_t ws_size,
                              hipStream_t stream) {
    (void)in_sizes; (void)n_in; (void)out_size; (void)ws_size;
    const float* x  = (const float*)d_in[0];
    const float* qw = (const float*)d_in[1];
    const float* kw = (const float*)d_in[2];
    const float* vw = (const float*)d_in[3];
    const float* ow = (const float*)d_in[4];
    const float* ve = (const float*)d_in[5];
    const float* v0 = (const float*)d_in[6];
    const float* qg = (const float*)d_in[7];
    const float* vl = (const float*)d_in[8];
    const float* gw = (const float*)d_in[9];
    const float* gb = (const float*)d_in[10];

    float* out  = (float*)d_out;
    float* rawv = out + (size_t)BB*TT*DD;

    // workspace layout (float units)
    float* ws   = (float*)d_ws;
    float* qkvp = ws;                               // 2 x 4096*1536 f32 split-K partials
    float* p    = ws + 2*6291456;
    short* x16  = (short*)p;        p += 2097152;   // 4096*1024 bf16
    short* wb16 = (short*)p;        p += 786432;    // 1536*1024 bf16 (qw|kw|vw)
    short* ow16 = (short*)p;        p += 524288;    // 1024*1024 bf16
    short* qbh  = (short*)p;        p += 2097152;   // [b*16+h][t][d] bf16
    short* kbh  = (short*)p;        p += 524288;    // [b*4+kvh][t][d] bf16
    short* vtb  = (short*)p;        p += 524288;    // [b*4+kvh][d][t] bf16
    short* vb   = (short*)p;        p += 524288;    // [b][t][kvh][d] bf16 (pre-transpose)
    float* gt   = p;                                // 4096*16 f32
    short* y16  = (short*)qkvp;                     // reuses partial region post-epilogue

    conv_all<<<6656, 256, 0, stream>>>(x, qw, kw, vw, ow, x16, wb16, ow16);
    // QKV projection: M=4096, N=1536, split-K=2 (z-dim), partials -> qkvp[z]
    gemm_mfma<<<dim3(12, 32, 2), 256, 0, stream>>>(x16, wb16, qkvp, 1536, 512);
    qkv_epilogue<<<24576, 256, 0, stream>>>(qkvp, qkvp + 6291456, ve, v0, qg, vl,
                                            qbh, kbh, vb, rawv);
    transpose_v<<<dim3(8, 32), 256, 0, stream>>>(vb, vtb);
    gate_kernel<<<4096, 256, 0, stream>>>(x, gw, gb, gt);
    flash_mfma<<<dim3(32, 32), 256, 0, stream>>>(qbh, kbh, vtb, gt, y16);
    // out projection: M=4096, N=1024, no split-K
    gemm_mfma<<<dim3(8, 32, 1), 256, 0, stream>>>(y16, ow16, out, 1024, 1024);
}

// Round 9
// 210.415 us; speedup vs baseline: 1.1290x; 1.0370x over previous
//
#include <hip/hip_runtime.h>
#include <math.h>

#define BB 2
#define TT 2048
#define DD 1024
#define NH 16
#define NKV 4
#define HD 64
#define EPSF 1.1920929e-07f
// T=2048 > TSL=1024 -> nb = 10000 * 2^(64/62); log2(nb) = log2(1e4) + 64/62
#define LOG2_NB 14.319970444065578
// 0.125 (1/sqrt(64)) * log2(e): folded into q so softmax runs in exp2 domain
#define SCALE_LOG2E 0.18033688011112042f
// fixed softmax max (exp2 units): |q.k| <= 8*8*1.5*0.125*log2e = 17.31 < 17.5
#define FIXMAX 17.5f

typedef __attribute__((ext_vector_type(8))) short bf16x8;
typedef __attribute__((ext_vector_type(4))) float f32x4;

__device__ inline short f2bf(float f) {
    unsigned u = __builtin_bit_cast(unsigned, f);
    unsigned r = (u + 0x7fffu + ((u >> 16) & 1u)) >> 16;
    return (short)r;
}
// packed f32x2 -> bf16x2 (hardware RNE rounding, 1 VALU op)
__device__ inline unsigned cvt_pk_bf16(float a, float b) {
    unsigned r;
    asm("v_cvt_pk_bf16_f32 %0, %1, %2" : "=v"(r) : "v"(a), "v"(b));
    return r;
}

// ---------------- fused fp32 -> bf16 conversion for all 5 tensors ----------------
__global__ __launch_bounds__(256) void conv_all(
    const float* __restrict__ x, const float* __restrict__ qw,
    const float* __restrict__ kw, const float* __restrict__ vw,
    const float* __restrict__ ow,
    short* __restrict__ x16, short* __restrict__ wb16, short* __restrict__ ow16)
{
    int i = blockIdx.x * 256 + threadIdx.x;   // float4 index, total 1703936
    const float* src; short* dst; int j;
    if (i < 1048576)      { src = x;  dst = x16;            j = i; }
    else if (i < 1310720) { src = qw; dst = wb16;           j = i - 1048576; }
    else if (i < 1376256) { src = kw; dst = wb16 + 1048576; j = i - 1310720; }
    else if (i < 1441792) { src = vw; dst = wb16 + 1310720; j = i - 1376256; }
    else                  { src = ow; dst = ow16;           j = i - 1441792; }
    float4 v = ((const float4*)src)[j];
    short4 o;
    o.x = f2bf(v.x); o.y = f2bf(v.y); o.z = f2bf(v.z); o.w = f2bf(v.w);
    ((short4*)dst)[j] = o;
}

// ---------------- bf16 MFMA GEMM: C = A * B^T over K range [z*klen, (z+1)*klen) ----------------
__global__ __launch_bounds__(256, 4) void gemm_mfma(
    const short* __restrict__ A, const short* __restrict__ Bmat,
    float* __restrict__ C, int ldc, int klen)
{
    __shared__ short As[2][128*32];
    __shared__ short Bs[2][128*32];
    int tid = threadIdx.x;
    int w = tid >> 6, lane = tid & 63;
    int quad = lane >> 4, lc = lane & 15;
    int wy = w >> 1, wx = w & 1;
    int m0 = blockIdx.y * 128, n0 = blockIdx.x * 128;
    int kbeg = blockIdx.z * klen, kend = kbeg + klen;
    float* Cz = C + (size_t)blockIdx.z * 4096 * ldc;

    f32x4 acc[4][4];
    #pragma unroll
    for (int i = 0; i < 4; i++)
        #pragma unroll
        for (int j = 0; j < 4; j++) acc[i][j] = (f32x4){0.f,0.f,0.f,0.f};

    #define GSTAGE(buf, k0)                                                             \
    {                                                                                   \
        _Pragma("unroll")                                                               \
        for (int i = 0; i < 2; i++) {                                                   \
            int off = w*2048 + i*1024;            /* byte offset, wave-uniform */       \
            int g = (off >> 4) + lane;            /* 16B chunk idx */                   \
            int row = g >> 2, c = g & 3;                                                \
            int cg = c ^ (row & 3);               /* XOR swizzle */                     \
            const short* ga = A + (size_t)(m0 + row)*1024 + (k0) + cg*8;                \
            __builtin_amdgcn_global_load_lds(                                           \
                (const __attribute__((address_space(1))) void*)ga,                      \
                (__attribute__((address_space(3))) void*)((char*)&As[buf][0] + off), 16, 0, 0); \
            const short* gb = Bmat + (size_t)(n0 + row)*1024 + (k0) + cg*8;             \
            __builtin_amdgcn_global_load_lds(                                           \
                (const __attribute__((address_space(1))) void*)gb,                      \
                (__attribute__((address_space(3))) void*)((char*)&Bs[buf][0] + off), 16, 0, 0); \
        }                                                                               \
    }

    GSTAGE(0, kbeg);
    __syncthreads();

    for (int k0 = kbeg; k0 < kend; k0 += 32) {
        int cur = ((k0 - kbeg) >> 5) & 1;

        // 1. LDS -> register fragment reads (before any new DMA is issued)
        bf16x8 af[4], bfr[4];
        #pragma unroll
        for (int tm = 0; tm < 4; tm++) {
            int row = wy*64 + tm*16 + lc;
            af[tm] = *(const bf16x8*)(&As[cur][0] + row*32 + ((quad*8) ^ ((row&3)*8)));
        }
        #pragma unroll
        for (int tn = 0; tn < 4; tn++) {
            int row = wx*64 + tn*16 + lc;
            bfr[tn] = *(const bf16x8*)(&Bs[cur][0] + row*32 + ((quad*8) ^ ((row&3)*8)));
        }
        // 2. prefetch next K-slice
        if (k0 + 32 < kend) GSTAGE(cur ^ 1, k0 + 32);
        // 3. compute
        #pragma unroll
        for (int tm = 0; tm < 4; tm++)
            #pragma unroll
            for (int tn = 0; tn < 4; tn++)
                acc[tm][tn] = __builtin_amdgcn_mfma_f32_16x16x32_bf16(af[tm], bfr[tn], acc[tm][tn], 0, 0, 0);
        // 4. barrier: drains the prefetch DMA after compute had its window
        __syncthreads();
    }

    #pragma unroll
    for (int tm = 0; tm < 4; tm++)
        #pragma unroll
        for (int r = 0; r < 4; r++) {
            int m = m0 + wy*64 + tm*16 + quad*4 + r;
            #pragma unroll
            for (int tn = 0; tn < 4; tn++) {
                int n = n0 + wx*64 + tn*16 + lc;
                Cz[(size_t)m*ldc + n] = acc[tm][tn][r];
            }
        }
}

// ---------------- epilogue: sum split-K partials; RMSNorm + RoPE + gain*scale (q,k) -> bf16;
// ---------------- v = p0+p1+ve, mix -> bf16; raw_v fp32 ----------------
__global__ __launch_bounds__(256) void qkv_epilogue(
    const float* __restrict__ qp0, const float* __restrict__ qp1,
    const float* __restrict__ ve, const float* __restrict__ v0,
    const float* __restrict__ q_gain, const float* __restrict__ vr_lambda,
    short* __restrict__ qbh, short* __restrict__ kbh, short* __restrict__ vb,
    float* __restrict__ rawv)
{
    int wave = blockIdx.x * 4 + (threadIdx.x >> 6);
    int lane = threadIdx.x & 63;
    int row = wave / 24;     // 0..4095  (b*T + t)
    int hh  = wave % 24;
    int b = row >> 11;
    int t = row & (TT - 1);

    if (hh < 20) {
        int col = (hh < 16) ? (hh*64 + lane) : (1024 + (hh-16)*64 + lane);
        size_t idx = (size_t)row*1536 + col;
        float val = qp0[idx] + qp1[idx];
        float ss = val * val;
        #pragma unroll
        for (int off = 32; off; off >>= 1) ss += __shfl_xor(ss, off);
        val *= rsqrtf(ss * (1.0f/64.0f) + EPSF);
        float partner = __shfl(val, lane ^ 32);
        int idxr = lane & 31;
        float inv = (float)exp2((double)idxr * (-LOG2_NB / 32.0));
        float fr = (float)t * inv;
        float sn, cs;
        sincosf(fr, &sn, &cs);
        float outv = (lane < 32) ? (val*cs + partner*sn) : (val*cs - partner*sn);
        if (hh < 16) {
            outv *= q_gain[hh] * SCALE_LOG2E;    // fold softmax scale+log2e into q
            qbh[(((size_t)(b*16 + hh))*2048 + t)*64 + lane] = f2bf(outv);
        } else {
            kbh[(((size_t)(b*4 + (hh-16)))*2048 + t)*64 + lane] = f2bf(outv);
        }
    } else {
        int vh = hh - 20;
        size_t off = ((size_t)row*4 + vh)*64 + lane;
        size_t idx = (size_t)row*1536 + 1280 + vh*64 + lane;
        float vraw = qp0[idx] + qp1[idx] + ve[off];
        rawv[off] = vraw;
        float vmix = vr_lambda[0]*v0[off] + vr_lambda[1]*vraw;
        vb[off] = f2bf(vmix);                    // coalesced [b][t][kvh][d]
    }
}

// ---------------- V transpose: vb [b][t][kvh][d] -> vtb [b*4+kvh][d][t] ----------------
__global__ __launch_bounds__(256) void transpose_v(
    const short* __restrict__ vb, short* __restrict__ vtb)
{
    __shared__ short tile[64][72];
    int bk = blockIdx.x;           // b*4+kvh
    int tt = blockIdx.y;           // t tile (64)
    int b = bk >> 2, kvh = bk & 3;
    int tid = threadIdx.x;
    int t4 = tid >> 4;             // 0..15
    int d4 = (tid & 15) * 4;       // 0..60
    #pragma unroll
    for (int i = 0; i < 4; i++) {
        int t = t4 + i*16;
        const short* src = vb + (((size_t)(b*2048 + tt*64 + t)*4 + kvh)*64 + d4);
        *(short4*)&tile[t][d4] = *(const short4*)src;
    }
    __syncthreads();
    #pragma unroll
    for (int i = 0; i < 4; i++) {
        int d = t4 + i*16;
        int t0 = d4;
        short4 o;
        o.x = tile[t0+0][d]; o.y = tile[t0+1][d];
        o.z = tile[t0+2][d]; o.w = tile[t0+3][d];
        *(short4*)&vtb[((size_t)(bk*64 + d))*2048 + tt*64 + t0] = o;
    }
}

// ---------------- gate: sigmoid(x @ gate_w.T + gate_b) ----------------
__global__ __launch_bounds__(256) void gate_kernel(
    const float* __restrict__ x, const float* __restrict__ gw,
    const float* __restrict__ gb, float* __restrict__ gate)
{
    __shared__ float xs[1024];
    int row = blockIdx.x;
    int tid = threadIdx.x;
    *(float4*)&xs[tid*4] = *(const float4*)&x[(size_t)row*1024 + tid*4];
    __syncthreads();
    int wave = tid >> 6, lane = tid & 63;
    for (int h = wave; h < 16; h += 4) {
        const float* w = gw + (size_t)h * 1024;
        float s = 0.f;
        #pragma unroll
        for (int i = 0; i < 16; i++) s += xs[lane + 64*i] * w[lane + 64*i];
        #pragma unroll
        for (int off = 32; off; off >>= 1) s += __shfl_xor(s, off);
        if (lane == 0) gate[(size_t)row*16 + h] = 1.0f / (1.0f + __expf(-(s + gb[h])));
    }
}

// ---------------- MFMA flash attention v4: raw v_exp, packed bf16 cvt, l via ones-MFMA ----------------
__global__ __launch_bounds__(256, 4) void flash_mfma(
    const short* __restrict__ qbh, const short* __restrict__ kbh,
    const short* __restrict__ vtb, const float* __restrict__ gate,
    short* __restrict__ y16)
{
    __shared__ short Ks[2][64*64];
    __shared__ short Vt[2][64*64];
    __shared__ short Ps[4][16*64];   // per wave: row q=lc (16), 64 keys; 8B-chunk XOR swizzle

    int bh = blockIdx.x;             // b*16 + h
    int b = bh >> 4, h = bh & 15, kvh = h >> 2;
    int qt = 31 - blockIdx.y;        // long blocks launch first
    int tid = threadIdx.x;
    int w = tid >> 6, lane = tid & 63;
    int quad = lane >> 4, lc = lane & 15;

    const short* qbase = qbh + (((size_t)bh)*2048 + qt*64 + w*16 + lc)*64;
    bf16x8 qf0 = *(const bf16x8*)(qbase + quad*8);
    bf16x8 qf1 = *(const bf16x8*)(qbase + 32 + quad*8);

    f32x4 o[4];
    #pragma unroll
    for (int i = 0; i < 4; i++) o[i] = (f32x4){0.f,0.f,0.f,0.f};
    f32x4 l4 = (f32x4){0.f,0.f,0.f,0.f};      // l in C-layout via P x ones MFMA
    const bf16x8 ones = {(short)0x3F80,(short)0x3F80,(short)0x3F80,(short)0x3F80,
                         (short)0x3F80,(short)0x3F80,(short)0x3F80,(short)0x3F80};

    const size_t kbase = ((size_t)(b*4 + kvh))*2048*64;   // K [t][d]
    const size_t vbase = ((size_t)(b*4 + kvh))*64*2048;   // V^T [d][t]

    #define STAGE(buf, kt)                                                              \
    {                                                                                   \
        _Pragma("unroll")                                                               \
        for (int i = 0; i < 2; i++) {                                                   \
            int off = w*2048 + i*1024;                                                  \
            int g = (off >> 4) + lane;                                                  \
            int row = g >> 3, c = g & 7;                                                \
            int cg = c ^ (row & 7);                                                     \
            const short* gk = kbh + kbase + (size_t)((kt)*64 + row)*64 + cg*8;          \
            __builtin_amdgcn_global_load_lds(                                           \
                (const __attribute__((address_space(1))) void*)gk,                      \
                (__attribute__((address_space(3))) void*)((char*)Ks[buf] + off), 16, 0, 0); \
            const short* gv = vtb + vbase + (size_t)row*2048 + (kt)*64 + cg*8;          \
            __builtin_amdgcn_global_load_lds(                                           \
                (const __attribute__((address_space(1))) void*)gv,                      \
                (__attribute__((address_space(3))) void*)((char*)Vt[buf] + off), 16, 0, 0); \
        }                                                                               \
    }

    STAGE(0, 0);
    __syncthreads();

    short* ps = Ps[w];

    for (int kt = 0; kt <= qt; kt++) {
        int cur = kt & 1;
        bool diag = (kt == qt);

        // 1. preload ALL K/V fragments for this tile (no LDS reads after DMA issue)
        bf16x8 kf0[4], kf1[4], vf0[4], vf1[4];
        #pragma unroll
        for (int kn = 0; kn < 4; kn++) {
            int row = kn*16 + lc;
            int sw = (row & 7) * 8;
            const short* kr = Ks[cur] + row*64;
            kf0[kn] = *(const bf16x8*)(kr + ((quad*8) ^ sw));
            kf1[kn] = *(const bf16x8*)(kr + ((quad*8 + 32) ^ sw));
            const short* vr = Vt[cur] + row*64;
            vf0[kn] = *(const bf16x8*)(vr + ((quad*8) ^ sw));
            vf1[kn] = *(const bf16x8*)(vr + ((quad*8 + 32) ^ sw));
        }
        // 2. prefetch next K/V tile
        if (kt < qt) STAGE(cur ^ 1, kt + 1);

        // 3. S^T = K Q^T : lane holds cols q=lc, rows key = kn*16 + quad*4 + r
        f32x4 s4[4];
        #pragma unroll
        for (int kn = 0; kn < 4; kn++) {
            f32x4 acc = (f32x4){0.f,0.f,0.f,0.f};
            acc = __builtin_amdgcn_mfma_f32_16x16x32_bf16(kf0[kn], qf0, acc, 0, 0, 0);
            acc = __builtin_amdgcn_mfma_f32_16x16x32_bf16(kf1[kn], qf1, acc, 0, 0, 0);
            s4[kn] = acc;
        }

        // 4. p = exp2(s - FIXMAX) (raw v_exp_f32), causal mask, packed cvt, b64 P store
        #pragma unroll
        for (int kn = 0; kn < 4; kn++) {
            float p0 = __builtin_amdgcn_exp2f(s4[kn][0] - FIXMAX);
            float p1 = __builtin_amdgcn_exp2f(s4[kn][1] - FIXMAX);
            float p2 = __builtin_amdgcn_exp2f(s4[kn][2] - FIXMAX);
            float p3 = __builtin_amdgcn_exp2f(s4[kn][3] - FIXMAX);
            if (diag) {
                int keyb = kn*16 + quad*4, qv = w*16 + lc;
                if (keyb + 0 > qv) p0 = 0.f;
                if (keyb + 1 > qv) p1 = 0.f;
                if (keyb + 2 > qv) p2 = 0.f;
                if (keyb + 3 > qv) p3 = 0.f;
            }
            int c = kn*4 + quad;
            int cs = c ^ ((lc & 7) << 1);
            int2 pk;
            pk.x = (int)cvt_pk_bf16(p0, p1);
            pk.y = (int)cvt_pk_bf16(p2, p3);
            *(int2*)(ps + lc*64 + cs*4) = pk;
        }
        __asm__ volatile("s_waitcnt lgkmcnt(0)" ::: "memory");
        // P A-frags: row q=lc, keys kh*32 + quad*8 + (0..7)
        int u0 = (0*4 + quad) ^ (lc & 7);
        int u1 = (1*4 + quad) ^ (lc & 7);
        bf16x8 pf0 = *(const bf16x8*)(ps + lc*64 + u0*8);
        bf16x8 pf1 = *(const bf16x8*)(ps + lc*64 + u1*8);

        // 5. O += P V ; l4 += P x ones (l lands in C-layout rows quad*4+r)
        #pragma unroll
        for (int dn = 0; dn < 4; dn++) {
            o[dn] = __builtin_amdgcn_mfma_f32_16x16x32_bf16(pf0, vf0[dn], o[dn], 0, 0, 0);
            o[dn] = __builtin_amdgcn_mfma_f32_16x16x32_bf16(pf1, vf1[dn], o[dn], 0, 0, 0);
        }
        l4 = __builtin_amdgcn_mfma_f32_16x16x32_bf16(pf0, ones, l4, 0, 0, 0);
        l4 = __builtin_amdgcn_mfma_f32_16x16x32_bf16(pf1, ones, l4, 0, 0, 0);
        __syncthreads();
    }

    #pragma unroll
    for (int r = 0; r < 4; r++) {
        int row = b*2048 + qt*64 + w*16 + quad*4 + r;
        float g = gate[(size_t)row*16 + h] / l4[r];
        #pragma unroll
        for (int dn = 0; dn < 4; dn++)
            y16[(size_t)row*1024 + h*64 + dn*16 + lc] = f2bf(o[dn][r] * g);
    }
}

extern "C" void kernel_launch(void* const* d_in, const int* in_sizes, int n_in,
                              void* d_out, int out_size, void* d_ws, size_t ws_size,
                              hipStream_t stream) {
    (void)in_sizes; (void)n_in; (void)out_size; (void)ws_size;
    const float* x  = (const float*)d_in[0];
    const float* qw = (const float*)d_in[1];
    const float* kw = (const float*)d_in[2];
    const float* vw = (const float*)d_in[3];
    const float* ow = (const float*)d_in[4];
    const float* ve = (const float*)d_in[5];
    const float* v0 = (const float*)d_in[6];
    const float* qg = (const float*)d_in[7];
    const float* vl = (const float*)d_in[8];
    const float* gw = (const float*)d_in[9];
    const float* gb = (const float*)d_in[10];

    float* out  = (float*)d_out;
    float* rawv = out + (size_t)BB*TT*DD;

    // workspace layout (float units)
    float* ws   = (float*)d_ws;
    float* qkvp = ws;                               // 2 x 4096*1536 f32 split-K partials
    float* p    = ws + 2*6291456;
    short* x16  = (short*)p;        p += 2097152;   // 4096*1024 bf16
    short* wb16 = (short*)p;        p += 786432;    // 1536*1024 bf16 (qw|kw|vw)
    short* ow16 = (short*)p;        p += 524288;    // 1024*1024 bf16
    short* qbh  = (short*)p;        p += 2097152;   // [b*16+h][t][d] bf16
    short* kbh  = (short*)p;        p += 524288;    // [b*4+kvh][t][d] bf16
    short* vtb  = (short*)p;        p += 524288;    // [b*4+kvh][d][t] bf16
    short* vb   = (short*)p;        p += 524288;    // [b][t][kvh][d] bf16 (pre-transpose)
    float* gt   = p;                                // 4096*16 f32
    short* y16  = (short*)qkvp;                     // reuses partial region post-epilogue

    conv_all<<<6656, 256, 0, stream>>>(x, qw, kw, vw, ow, x16, wb16, ow16);
    // QKV projection: M=4096, N=1536, split-K=2 (z-dim), partials -> qkvp[z]
    gemm_mfma<<<dim3(12, 32, 2), 256, 0, stream>>>(x16, wb16, qkvp, 1536, 512);
    qkv_epilogue<<<24576, 256, 0, stream>>>(qkvp, qkvp + 6291456, ve, v0, qg, vl,
                                            qbh, kbh, vb, rawv);
    transpose_v<<<dim3(8, 32), 256, 0, stream>>>(vb, vtb);
    gate_kernel<<<4096, 256, 0, stream>>>(x, gw, gb, gt);
    flash_mfma<<<dim3(32, 32), 256, 0, stream>>>(qbh, kbh, vtb, gt, y16);
    // out projection: M=4096, N=1024, no split-K
    gemm_mfma<<<dim3(8, 32, 1), 256, 0, stream>>>(y16, ow16, out, 1024, 1024);
}